// Round 6
// baseline (327.127 us; speedup 1.0000x reference)
//
#include <hip/hip_runtime.h>
#include <cstdint>

#define LT 24
#define NSITE (LT*LT*LT*LT)      // 331776
#define HALF  (NSITE/2)          // 165888
#define NCOMPLEX (4*NSITE*9)     // 11943936 complex elements total

#define BS   64                  // 1 wave per block: fine-grained CU balance
#define NBLK (HALF/BS)           // 2592 blocks -> 10-11 waves/CU
#define Q0D  (NSITE*9/2)         // 1492992: first out-quad of dir 1
// dirs 1-3 hold 3*NSITE*9/2 = 4478976 out-quads = 27 per update thread

typedef float vf4 __attribute__((ext_vector_type(4)));

struct C3 { float re[9]; float im[9]; };

// 9 contiguous floats, base only guaranteed 4B-aligned.
__device__ __forceinline__ void load9(float* d, const float* __restrict__ p) {
    float4 a, b;
    __builtin_memcpy(&a, p,     16);
    __builtin_memcpy(&b, p + 4, 16);
    d[0]=a.x; d[1]=a.y; d[2]=a.z; d[3]=a.w;
    d[4]=b.x; d[5]=b.y; d[6]=b.z; d[7]=b.w;
    d[8]=p[8];
}

__device__ __forceinline__ void loadM(C3& m, const float* __restrict__ re,
                                      const float* __restrict__ im, int off) {
    load9(m.re, re + off);
    load9(m.im, im + off);
}

// store matrix as interleaved (re,im) pairs at complex-element base cbase.
__device__ __forceinline__ void storeM(float2* __restrict__ out, int cbase, const C3& m) {
    float4 v;
    v.x=m.re[0]; v.y=m.im[0]; v.z=m.re[1]; v.w=m.im[1];
    __builtin_memcpy(out + cbase,     &v, 16);
    v.x=m.re[2]; v.y=m.im[2]; v.z=m.re[3]; v.w=m.im[3];
    __builtin_memcpy(out + cbase + 2, &v, 16);
    v.x=m.re[4]; v.y=m.im[4]; v.z=m.re[5]; v.w=m.im[5];
    __builtin_memcpy(out + cbase + 4, &v, 16);
    v.x=m.re[6]; v.y=m.im[6]; v.z=m.re[7]; v.w=m.im[7];
    __builtin_memcpy(out + cbase + 6, &v, 16);
    float2 w; w.x=m.re[8]; w.y=m.im[8];
    out[cbase + 8] = w;
}

// o = a @ b
__device__ __forceinline__ void mmul(C3& o, const C3& a, const C3& b) {
#pragma unroll
    for (int r = 0; r < 3; ++r) {
#pragma unroll
        for (int c = 0; c < 3; ++c) {
            float sr = 0.f, si = 0.f;
#pragma unroll
            for (int k = 0; k < 3; ++k) {
                float ar = a.re[r*3+k], ai = a.im[r*3+k];
                float br = b.re[k*3+c], bi = b.im[k*3+c];
                sr += ar*br - ai*bi;
                si += ar*bi + ai*br;
            }
            o.re[r*3+c] = sr; o.im[r*3+c] = si;
        }
    }
}

// f += cr * (a @ b)
__device__ __forceinline__ void mmul_acc(C3& f, const C3& a, const C3& b, float cr) {
#pragma unroll
    for (int r = 0; r < 3; ++r) {
#pragma unroll
        for (int c = 0; c < 3; ++c) {
            float sr = 0.f, si = 0.f;
#pragma unroll
            for (int k = 0; k < 3; ++k) {
                float ar = a.re[r*3+k], ai = a.im[r*3+k];
                float br = b.re[k*3+c], bi = b.im[k*3+c];
                sr += ar*br - ai*bi;
                si += ar*bi + ai*br;
            }
            f.re[r*3+c] += cr * sr; f.im[r*3+c] += cr * si;
        }
    }
}

// o = a @ b^dagger
__device__ __forceinline__ void mmul_adjB(C3& o, const C3& a, const C3& b) {
#pragma unroll
    for (int r = 0; r < 3; ++r) {
#pragma unroll
        for (int c = 0; c < 3; ++c) {
            float sr = 0.f, si = 0.f;
#pragma unroll
            for (int k = 0; k < 3; ++k) {
                float ar = a.re[r*3+k], ai = a.im[r*3+k];
                float br = b.re[c*3+k], bi = b.im[c*3+k];
                sr += ar*br + ai*bi;
                si += ai*br - ar*bi;
            }
            o.re[r*3+c] = sr; o.im[r*3+c] = si;
        }
    }
}

// o = a^dagger @ b
__device__ __forceinline__ void madjA_mul(C3& o, const C3& a, const C3& b) {
#pragma unroll
    for (int r = 0; r < 3; ++r) {
#pragma unroll
        for (int c = 0; c < 3; ++c) {
            float sr = 0.f, si = 0.f;
#pragma unroll
            for (int k = 0; k < 3; ++k) {
                float ar = a.re[k*3+r], ai = a.im[k*3+r];
                float br = b.re[k*3+c], bi = b.im[k*3+c];
                sr += ar*br + ai*bi;
                si += ar*bi - ai*br;
            }
            o.re[r*3+c] = sr; o.im[r*3+c] = si;
        }
    }
}

// idx in [0, HALF) -> site of given parity (0=even updated subset, 1=odd)
__device__ __forceinline__ int site_from_idx(int idx, int parity,
                                             int& t, int& z, int& y, int& x) {
    int xh = idx % 12;  int r = idx / 12;
    y = r % LT; r /= LT;
    z = r % LT; t = r / LT;
    x = 2 * xh + ((t + z + y + parity) & 1);
    return ((t * LT + z) * LT + y) * LT + x;
}

// ---- Fused kernel: every thread does update + its share of the copy --------
// Thread tidg in [0, HALF):
//   * stout update of even site tidg (dir 0)
//   * pass-through copy of odd site tidg (dir 0)           [1:1 mapping]
//   * 27 dense out-quads of dirs 1-3 (= exactly 3*NSITE*9/2 / HALF),
//     interleaved 9-per-staple-iteration so the copy's independent
//     loads/stores fill the staple loads' latency shadow (ILP overlap,
//     uniform across all waves -> no phase separation, no CU imbalance).
// launch_bounds(64,3): 1-wave blocks for balance; VGPR cap 170 (3 waves/SIMD).
// Round 4 lesson: never cap below ~150 (matexp needs ~90 floats live).
__global__ __launch_bounds__(BS, 3)
void stout_all(const float* __restrict__ xre, const float* __restrict__ xim,
               const float* __restrict__ coeff, float2* __restrict__ out) {
    const int tidg = blockIdx.x * BS + threadIdx.x;   // [0, HALF)

    const float2* __restrict__ re2 = (const float2*)xre;
    const float2* __restrict__ im2 = (const float2*)xim;
    vf4* __restrict__ o4 = (vf4*)out;

    // ---- odd-site dir-0 pass-through (independent: issue loads first) ----
    int t1, z1, y1, x1;
    const int s1 = site_from_idx(tidg, 1, t1, z1, y1, x1);
    C3 modd;
    loadM(modd, xre, xim, s1 * 9);

    // scaled coefficients: (2/pi)*0.75*atan(coeff)/6
    float c[6];
#pragma unroll
    for (int i = 0; i < 6; ++i)
        c[i] = 0.07957747154594768f * atanf(coeff[i]);

    // ---- even-site neighbor indices ----
    int t, z, y, x;
    const int s = site_from_idx(tidg, 0, t, z, y, x);

    int tp = (t + 1 < LT) ? t + 1 : 0;
    int zp = (z + 1 < LT) ? z + 1 : 0;  int zm = (z > 0) ? z - 1 : LT - 1;
    int yp = (y + 1 < LT) ? y + 1 : 0;  int ym = (y > 0) ? y - 1 : LT - 1;
    int xp = (x + 1 < LT) ? x + 1 : 0;  int xm = (x > 0) ? x - 1 : LT - 1;

    const int stt = ((tp * LT + z) * LT + y) * LT + x;   // s + T^
    const int spv[3]  = { ((t  * LT + zp) * LT + y ) * LT + x,
                          ((t  * LT + z ) * LT + yp) * LT + x,
                          ((t  * LT + z ) * LT + y ) * LT + xp };
    const int smv[3]  = { ((t  * LT + zm) * LT + y ) * LT + x,
                          ((t  * LT + z ) * LT + ym) * LT + x,
                          ((t  * LT + z ) * LT + y ) * LT + xm };
    const int smtv[3] = { ((tp * LT + zm) * LT + y ) * LT + x,
                          ((tp * LT + z ) * LT + ym) * LT + x,
                          ((tp * LT + z ) * LT + y ) * LT + xm };

    storeM(out, s1 * 9, modd);     // retire the odd copy

    C3 f;
#pragma unroll
    for (int j = 0; j < 9; ++j) { f.re[j] = 0.f; f.im[j] = 0.f; }

    C3 A, B, Cm, tmp;
#pragma unroll
    for (int i = 0; i < 3; ++i) {
        const int d = i + 1;
        // forward staple: x[nu](s) @ (x0(s+nu) @ x[nu](s+T)^dag)
        loadM(A, xre, xim, (d * NSITE + s) * 9);
        loadM(B,  xre, xim, (     spv[i])        * 9);
        loadM(Cm, xre, xim, (d * NSITE + stt)    * 9);
        mmul_adjB(tmp, B, Cm);
        mmul_acc(f, A, tmp, c[2 * i]);
        // backward staple: (x[nu](s-nu)^dag @ x0(s-nu)) @ x[nu](s-nu+T)
        loadM(A,  xre, xim, (d * NSITE + smv[i]) * 9);
        loadM(B,  xre, xim, (     smv[i])        * 9);
        madjA_mul(tmp, A, B);
        loadM(Cm, xre, xim, (d * NSITE + smtv[i])* 9);
        mmul_acc(f, tmp, Cm, c[2 * i + 1]);

        // ---- 9 dense interleave-copy quads of dirs 1-3 (independent work
        //      that overlaps the next iteration's staple-load latency) ----
#pragma unroll
        for (int j = 0; j < 9; ++j) {
            const int q = Q0D + (i * 9 + j) * HALF + tidg;
            float2 r  = re2[q];
            float2 im = im2[q];
            vf4 o = { r.x, im.x, r.y, im.y };
            __builtin_nontemporal_store(o, o4 + q);
        }
    }

    // xupd = x0(s) (even site)
    C3 U;
    loadM(U, xre, xim, s * 9);

    // M = f @ U^dag ; A = 0.5(M - M^dag) ; Zt = A - tr(A)/3 * I
    C3 Mm;
    mmul_adjB(Mm, f, U);
    C3 Zt;
#pragma unroll
    for (int r = 0; r < 3; ++r) {
#pragma unroll
        for (int cq = 0; cq < 3; ++cq) {
            Zt.re[r*3+cq] = 0.5f * (Mm.re[r*3+cq] - Mm.re[cq*3+r]);
            Zt.im[r*3+cq] = 0.5f * (Mm.im[r*3+cq] + Mm.im[cq*3+r]);
        }
    }
    float trIm = (Zt.im[0] + Zt.im[4] + Zt.im[8]) / 3.0f;
    Zt.im[0] -= trIm; Zt.im[4] -= trIm; Zt.im[8] -= trIm;

    // matexp: scale by 0.5^4, 12-term Horner, 4 squarings
#pragma unroll
    for (int j = 0; j < 9; ++j) { Zt.re[j] *= 0.0625f; Zt.im[j] *= 0.0625f; }

    C3 E;
#pragma unroll
    for (int j = 0; j < 9; ++j) { E.re[j] = 0.f; E.im[j] = 0.f; }
    E.re[0] = 1.f; E.re[4] = 1.f; E.re[8] = 1.f;

    C3 Tm;
#pragma unroll
    for (int k = 12; k >= 1; --k) {
        mmul(Tm, Zt, E);
        const float invk = 1.0f / (float)k;
#pragma unroll
        for (int j = 0; j < 9; ++j) {
            E.re[j] = Tm.re[j] * invk;
            E.im[j] = Tm.im[j] * invk;
        }
        E.re[0] += 1.f; E.re[4] += 1.f; E.re[8] += 1.f;
    }
#pragma unroll
    for (int q = 0; q < 4; ++q) {
        mmul(Tm, E, E);
        E = Tm;
    }

    // ymu = E @ U  (even site: xmu_fix = 0)
    C3 Y;
    mmul(Y, E, U);
    storeM(out, s * 9, Y);   // dir-0 updated link
}

extern "C" void kernel_launch(void* const* d_in, const int* in_sizes, int n_in,
                              void* d_out, int out_size, void* d_ws, size_t ws_size,
                              hipStream_t stream) {
    const float* xre   = (const float*)d_in[0];
    const float* xim   = (const float*)d_in[1];
    const float* coeff = (const float*)d_in[2];

    stout_all<<<NBLK, BS, 0, stream>>>(xre, xim, coeff, (float2*)d_out);
}

// Round 7
// 238.855 us; speedup vs baseline: 1.3696x; 1.3696x over previous
//
#include <hip/hip_runtime.h>
#include <cstdint>

#define LT 24
#define NSITE (LT*LT*LT*LT)      // 331776
#define HALF  (NSITE/2)          // 165888
#define NCOMPLEX (4*NSITE*9)     // 11943936 complex elements total

#define BS   64                  // 1 wave per block: fine-grained CU balance
#define NBLK (HALF/BS)           // 2592 blocks -> 10-11 waves/CU
#define Q0D  (NSITE*9/2)         // 1492992: first out-quad of dir 1
// dirs 1-3 hold 3*NSITE*9/2 = 4478976 out-quads = 27 per update thread

typedef float vf4 __attribute__((ext_vector_type(4)));

struct C3 { float re[9]; float im[9]; };

// 9 contiguous floats, base only guaranteed 4B-aligned.
__device__ __forceinline__ void load9(float* d, const float* __restrict__ p) {
    float4 a, b;
    __builtin_memcpy(&a, p,     16);
    __builtin_memcpy(&b, p + 4, 16);
    d[0]=a.x; d[1]=a.y; d[2]=a.z; d[3]=a.w;
    d[4]=b.x; d[5]=b.y; d[6]=b.z; d[7]=b.w;
    d[8]=p[8];
}

__device__ __forceinline__ void loadM(C3& m, const float* __restrict__ re,
                                      const float* __restrict__ im, int off) {
    load9(m.re, re + off);
    load9(m.im, im + off);
}

// store matrix as interleaved (re,im) pairs at complex-element base cbase.
__device__ __forceinline__ void storeM(float2* __restrict__ out, int cbase, const C3& m) {
    float4 v;
    v.x=m.re[0]; v.y=m.im[0]; v.z=m.re[1]; v.w=m.im[1];
    __builtin_memcpy(out + cbase,     &v, 16);
    v.x=m.re[2]; v.y=m.im[2]; v.z=m.re[3]; v.w=m.im[3];
    __builtin_memcpy(out + cbase + 2, &v, 16);
    v.x=m.re[4]; v.y=m.im[4]; v.z=m.re[5]; v.w=m.im[5];
    __builtin_memcpy(out + cbase + 4, &v, 16);
    v.x=m.re[6]; v.y=m.im[6]; v.z=m.re[7]; v.w=m.im[7];
    __builtin_memcpy(out + cbase + 6, &v, 16);
    float2 w; w.x=m.re[8]; w.y=m.im[8];
    out[cbase + 8] = w;
}

// o = a @ b
__device__ __forceinline__ void mmul(C3& o, const C3& a, const C3& b) {
#pragma unroll
    for (int r = 0; r < 3; ++r) {
#pragma unroll
        for (int c = 0; c < 3; ++c) {
            float sr = 0.f, si = 0.f;
#pragma unroll
            for (int k = 0; k < 3; ++k) {
                float ar = a.re[r*3+k], ai = a.im[r*3+k];
                float br = b.re[k*3+c], bi = b.im[k*3+c];
                sr += ar*br - ai*bi;
                si += ar*bi + ai*br;
            }
            o.re[r*3+c] = sr; o.im[r*3+c] = si;
        }
    }
}

// f += cr * (a @ b)
__device__ __forceinline__ void mmul_acc(C3& f, const C3& a, const C3& b, float cr) {
#pragma unroll
    for (int r = 0; r < 3; ++r) {
#pragma unroll
        for (int c = 0; c < 3; ++c) {
            float sr = 0.f, si = 0.f;
#pragma unroll
            for (int k = 0; k < 3; ++k) {
                float ar = a.re[r*3+k], ai = a.im[r*3+k];
                float br = b.re[k*3+c], bi = b.im[k*3+c];
                sr += ar*br - ai*bi;
                si += ar*bi + ai*br;
            }
            f.re[r*3+c] += cr * sr; f.im[r*3+c] += cr * si;
        }
    }
}

// o = a @ b^dagger
__device__ __forceinline__ void mmul_adjB(C3& o, const C3& a, const C3& b) {
#pragma unroll
    for (int r = 0; r < 3; ++r) {
#pragma unroll
        for (int c = 0; c < 3; ++c) {
            float sr = 0.f, si = 0.f;
#pragma unroll
            for (int k = 0; k < 3; ++k) {
                float ar = a.re[r*3+k], ai = a.im[r*3+k];
                float br = b.re[c*3+k], bi = b.im[c*3+k];
                sr += ar*br + ai*bi;
                si += ai*br - ar*bi;
            }
            o.re[r*3+c] = sr; o.im[r*3+c] = si;
        }
    }
}

// o = a^dagger @ b
__device__ __forceinline__ void madjA_mul(C3& o, const C3& a, const C3& b) {
#pragma unroll
    for (int r = 0; r < 3; ++r) {
#pragma unroll
        for (int c = 0; c < 3; ++c) {
            float sr = 0.f, si = 0.f;
#pragma unroll
            for (int k = 0; k < 3; ++k) {
                float ar = a.re[k*3+r], ai = a.im[k*3+r];
                float br = b.re[k*3+c], bi = b.im[k*3+c];
                sr += ar*br + ai*bi;
                si += ar*bi - ai*br;
            }
            o.re[r*3+c] = sr; o.im[r*3+c] = si;
        }
    }
}

// idx in [0, HALF) -> site of given parity (0=even updated subset, 1=odd)
__device__ __forceinline__ int site_from_idx(int idx, int parity,
                                             int& t, int& z, int& y, int& x) {
    int xh = idx % 12;  int r = idx / 12;
    y = r % LT; r /= LT;
    z = r % LT; t = r / LT;
    x = 2 * xh + ((t + z + y + parity) & 1);
    return ((t * LT + z) * LT + y) * LT + x;
}

// ---- Fused kernel: every thread does update + its share of the copy --------
// Thread tidg in [0, HALF):
//   * stout update of even site tidg (dir 0)
//   * pass-through copy of odd site tidg (dir 0)           [1:1 mapping]
//   * 27 dense out-quads of dirs 1-3, interleaved 9-per-staple-iteration so
//     the copy's independent loads/stores fill the staple-load latency shadow
//     (ILP overlap, uniform across all waves -> no phase separation).
// NO min-waves occupancy bound: rounds 4 & 6 both proved any VGPR cap below
// ~150 spills matexp catastrophically (WRITE_SIZE 101 -> 315/418 MB).
// Round-5 uncapped baseline: VGPR=152, zero spill. Let the compiler pick.
__global__ __launch_bounds__(BS)
void stout_all(const float* __restrict__ xre, const float* __restrict__ xim,
               const float* __restrict__ coeff, float2* __restrict__ out) {
    const int tidg = blockIdx.x * BS + threadIdx.x;   // [0, HALF)

    const float2* __restrict__ re2 = (const float2*)xre;
    const float2* __restrict__ im2 = (const float2*)xim;
    vf4* __restrict__ o4 = (vf4*)out;

    // ---- odd-site dir-0 pass-through (independent: issue loads first) ----
    int t1, z1, y1, x1;
    const int s1 = site_from_idx(tidg, 1, t1, z1, y1, x1);
    C3 modd;
    loadM(modd, xre, xim, s1 * 9);

    // scaled coefficients: (2/pi)*0.75*atan(coeff)/6
    float c[6];
#pragma unroll
    for (int i = 0; i < 6; ++i)
        c[i] = 0.07957747154594768f * atanf(coeff[i]);

    // ---- even-site neighbor indices ----
    int t, z, y, x;
    const int s = site_from_idx(tidg, 0, t, z, y, x);

    int tp = (t + 1 < LT) ? t + 1 : 0;
    int zp = (z + 1 < LT) ? z + 1 : 0;  int zm = (z > 0) ? z - 1 : LT - 1;
    int yp = (y + 1 < LT) ? y + 1 : 0;  int ym = (y > 0) ? y - 1 : LT - 1;
    int xp = (x + 1 < LT) ? x + 1 : 0;  int xm = (x > 0) ? x - 1 : LT - 1;

    const int stt = ((tp * LT + z) * LT + y) * LT + x;   // s + T^
    const int spv[3]  = { ((t  * LT + zp) * LT + y ) * LT + x,
                          ((t  * LT + z ) * LT + yp) * LT + x,
                          ((t  * LT + z ) * LT + y ) * LT + xp };
    const int smv[3]  = { ((t  * LT + zm) * LT + y ) * LT + x,
                          ((t  * LT + z ) * LT + ym) * LT + x,
                          ((t  * LT + z ) * LT + y ) * LT + xm };
    const int smtv[3] = { ((tp * LT + zm) * LT + y ) * LT + x,
                          ((tp * LT + z ) * LT + ym) * LT + x,
                          ((tp * LT + z ) * LT + y ) * LT + xm };

    storeM(out, s1 * 9, modd);     // retire the odd copy

    C3 f;
#pragma unroll
    for (int j = 0; j < 9; ++j) { f.re[j] = 0.f; f.im[j] = 0.f; }

    C3 A, B, Cm, tmp;
#pragma unroll
    for (int i = 0; i < 3; ++i) {
        const int d = i + 1;
        // forward staple: x[nu](s) @ (x0(s+nu) @ x[nu](s+T)^dag)
        loadM(A, xre, xim, (d * NSITE + s) * 9);
        loadM(B,  xre, xim, (     spv[i])        * 9);
        loadM(Cm, xre, xim, (d * NSITE + stt)    * 9);
        mmul_adjB(tmp, B, Cm);
        mmul_acc(f, A, tmp, c[2 * i]);
        // backward staple: (x[nu](s-nu)^dag @ x0(s-nu)) @ x[nu](s-nu+T)
        loadM(A,  xre, xim, (d * NSITE + smv[i]) * 9);
        loadM(B,  xre, xim, (     smv[i])        * 9);
        madjA_mul(tmp, A, B);
        loadM(Cm, xre, xim, (d * NSITE + smtv[i])* 9);
        mmul_acc(f, tmp, Cm, c[2 * i + 1]);

        // ---- 9 dense interleave-copy quads of dirs 1-3 (independent work
        //      that overlaps the next iteration's staple-load latency) ----
#pragma unroll
        for (int j = 0; j < 9; ++j) {
            const int q = Q0D + (i * 9 + j) * HALF + tidg;
            float2 r  = re2[q];
            float2 im = im2[q];
            vf4 o = { r.x, im.x, r.y, im.y };
            __builtin_nontemporal_store(o, o4 + q);
        }
    }

    // xupd = x0(s) (even site)
    C3 U;
    loadM(U, xre, xim, s * 9);

    // M = f @ U^dag ; A = 0.5(M - M^dag) ; Zt = A - tr(A)/3 * I
    C3 Mm;
    mmul_adjB(Mm, f, U);
    C3 Zt;
#pragma unroll
    for (int r = 0; r < 3; ++r) {
#pragma unroll
        for (int cq = 0; cq < 3; ++cq) {
            Zt.re[r*3+cq] = 0.5f * (Mm.re[r*3+cq] - Mm.re[cq*3+r]);
            Zt.im[r*3+cq] = 0.5f * (Mm.im[r*3+cq] + Mm.im[cq*3+r]);
        }
    }
    float trIm = (Zt.im[0] + Zt.im[4] + Zt.im[8]) / 3.0f;
    Zt.im[0] -= trIm; Zt.im[4] -= trIm; Zt.im[8] -= trIm;

    // matexp: scale by 0.5^4, 12-term Horner, 4 squarings
#pragma unroll
    for (int j = 0; j < 9; ++j) { Zt.re[j] *= 0.0625f; Zt.im[j] *= 0.0625f; }

    C3 E;
#pragma unroll
    for (int j = 0; j < 9; ++j) { E.re[j] = 0.f; E.im[j] = 0.f; }
    E.re[0] = 1.f; E.re[4] = 1.f; E.re[8] = 1.f;

    C3 Tm;
#pragma unroll
    for (int k = 12; k >= 1; --k) {
        mmul(Tm, Zt, E);
        const float invk = 1.0f / (float)k;
#pragma unroll
        for (int j = 0; j < 9; ++j) {
            E.re[j] = Tm.re[j] * invk;
            E.im[j] = Tm.im[j] * invk;
        }
        E.re[0] += 1.f; E.re[4] += 1.f; E.re[8] += 1.f;
    }
#pragma unroll
    for (int q = 0; q < 4; ++q) {
        mmul(Tm, E, E);
        E = Tm;
    }

    // ymu = E @ U  (even site: xmu_fix = 0)
    C3 Y;
    mmul(Y, E, U);
    storeM(out, s * 9, Y);   // dir-0 updated link
}

extern "C" void kernel_launch(void* const* d_in, const int* in_sizes, int n_in,
                              void* d_out, int out_size, void* d_ws, size_t ws_size,
                              hipStream_t stream) {
    const float* xre   = (const float*)d_in[0];
    const float* xim   = (const float*)d_in[1];
    const float* coeff = (const float*)d_in[2];

    stout_all<<<NBLK, BS, 0, stream>>>(xre, xim, coeff, (float2*)d_out);
}